// Round 1
// baseline (50332.870 us; speedup 1.0000x reference)
//
#include <hip/hip_runtime.h>
#include <math.h>

#define NPART 2048
#define DT 0.016f

// One block per particle i; 256 threads; thread t handles j = t, t+256, ...
// Weights staged in LDS, read at wave-uniform addresses (broadcast).
// All activation arrays fully unrolled -> registers.
__global__ __launch_bounds__(256) void particle_step_kernel(
    const float* __restrict__ ext,    // [N,3]
    const float* __restrict__ pos,    // [N,3]
    const float* __restrict__ vel,    // [N,3]
    const float* __restrict__ mass,   // [N]
    const float* __restrict__ elast,  // [N]
    const float* __restrict__ fric,   // [N]
    const float* __restrict__ W1, const float* __restrict__ b1,   // [8,64],[64]
    const float* __restrict__ W2, const float* __restrict__ b2,   // [64,64],[64]
    const float* __restrict__ W3, const float* __restrict__ b3,   // [64,32],[32]
    const float* __restrict__ W4, const float* __restrict__ b4,   // [32,3],[3]
    float* __restrict__ out)          // [2*N*3]: new_pos then new_vel
{
    __shared__ float sW1[8 * 64];
    __shared__ float sb1[64];
    __shared__ float sW2[64 * 64];
    __shared__ float sb2[64];
    __shared__ float sW3[64 * 32];
    __shared__ float sb3[32];
    __shared__ float sW4[32 * 3];
    __shared__ float sb4[3];
    __shared__ float red[4][3];

    const int tid = threadIdx.x;
    const int i = blockIdx.x;

    // ---- stage weights into LDS ----
    for (int t = tid; t < 8 * 64; t += 256)  sW1[t] = W1[t];
    for (int t = tid; t < 64 * 64; t += 256) sW2[t] = W2[t];
    for (int t = tid; t < 64 * 32; t += 256) sW3[t] = W3[t];
    if (tid < 64) { sb1[tid] = b1[tid]; sb2[tid] = b2[tid]; }
    if (tid < 32) { sb3[tid] = b3[tid]; }
    if (tid < 96) { sW4[tid] = W4[tid]; }
    if (tid < 3)  { sb4[tid] = b4[tid]; }
    __syncthreads();

    const float pix = pos[i * 3 + 0], piy = pos[i * 3 + 1], piz = pos[i * 3 + 2];
    const float vix = vel[i * 3 + 0], viy = vel[i * 3 + 1], viz = vel[i * 3 + 2];
    const float mi = mass[i];

    float fx = 0.f, fy = 0.f, fz = 0.f;

    for (int jj = 0; jj < NPART; jj += 256) {
        const int j = jj + tid;
        const float pjx = pos[j * 3 + 0], pjy = pos[j * 3 + 1], pjz = pos[j * 3 + 2];
        const float vjx = vel[j * 3 + 0], vjy = vel[j * 3 + 1], vjz = vel[j * 3 + 2];
        const float mj = mass[j];

        // feat = [pos_j - pos_i, vel_j - vel_i, dist, m_i/m_j]
        const float rx = pjx - pix, ry = pjy - piy, rz = pjz - piz;
        const float sx = vjx - vix, sy = vjy - viy, sz = vjz - viz;
        const float d2 = rx * rx + ry * ry + rz * rz;
        const float dist = sqrtf(d2);
        const float ratio = mi / mj;
        const bool valid = (dist < 1.0f) && (j != i);

        float feat[8] = { rx, ry, rz, sx, sy, sz, dist, ratio };

        // ---- layer 1: 8 -> 64, relu ----
        float h1[64];
        #pragma unroll
        for (int m = 0; m < 64; ++m) h1[m] = sb1[m];
        #pragma unroll
        for (int d = 0; d < 8; ++d) {
            const float a = feat[d];
            #pragma unroll
            for (int m = 0; m < 64; ++m) h1[m] = fmaf(a, sW1[d * 64 + m], h1[m]);
        }
        #pragma unroll
        for (int m = 0; m < 64; ++m) h1[m] = fmaxf(h1[m], 0.f);

        // ---- layer 2: 64 -> 64, relu ----
        float h2[64];
        #pragma unroll
        for (int m = 0; m < 64; ++m) h2[m] = sb2[m];
        #pragma unroll
        for (int k = 0; k < 64; ++k) {
            const float a = h1[k];
            #pragma unroll
            for (int m = 0; m < 64; ++m) h2[m] = fmaf(a, sW2[k * 64 + m], h2[m]);
        }
        #pragma unroll
        for (int m = 0; m < 64; ++m) h2[m] = fmaxf(h2[m], 0.f);

        // ---- layer 3: 64 -> 32, relu ----
        float h3[32];
        #pragma unroll
        for (int m = 0; m < 32; ++m) h3[m] = sb3[m];
        #pragma unroll
        for (int k = 0; k < 64; ++k) {
            const float a = h2[k];
            #pragma unroll
            for (int m = 0; m < 32; ++m) h3[m] = fmaf(a, sW3[k * 32 + m], h3[m]);
        }
        #pragma unroll
        for (int m = 0; m < 32; ++m) h3[m] = fmaxf(h3[m], 0.f);

        // ---- layer 4: 32 -> 3, tanh * 10 ----
        float o0 = sb4[0], o1 = sb4[1], o2 = sb4[2];
        #pragma unroll
        for (int k = 0; k < 32; ++k) {
            const float a = h3[k];
            o0 = fmaf(a, sW4[k * 3 + 0], o0);
            o1 = fmaf(a, sW4[k * 3 + 1], o1);
            o2 = fmaf(a, sW4[k * 3 + 2], o2);
        }
        const float e0 = tanhf(o0) * 10.f;
        const float e1 = tanhf(o1) * 10.f;
        const float e2 = tanhf(o2) * 10.f;

        if (valid) { fx += e0; fy += e1; fz += e2; }
    }

    // ---- block reduction of (fx,fy,fz) over 256 threads ----
    #pragma unroll
    for (int off = 32; off > 0; off >>= 1) {
        fx += __shfl_down(fx, off);
        fy += __shfl_down(fy, off);
        fz += __shfl_down(fz, off);
    }
    const int wid = tid >> 6;
    if ((tid & 63) == 0) { red[wid][0] = fx; red[wid][1] = fy; red[wid][2] = fz; }
    __syncthreads();

    if (tid == 0) {
        float Fx = red[0][0] + red[1][0] + red[2][0] + red[3][0];
        float Fy = red[0][1] + red[1][1] + red[2][1] + red[3][1];
        float Fz = red[0][2] + red[1][2] + red[2][2] + red[3][2];

        // forces = gravity*mass + external + neural
        Fx += ext[i * 3 + 0];
        Fy += ext[i * 3 + 1] + (-9.8f) * mi;
        Fz += ext[i * 3 + 2];

        const float inv_m = 1.0f / mi;
        float nvx = vix + Fx * inv_m * DT;
        float nvy = viy + Fy * inv_m * DT;
        float nvz = viz + Fz * inv_m * DT;

        // friction where |v| > 0.1
        const float speed = sqrtf(nvx * nvx + nvy * nvy + nvz * nvz);
        if (speed > 0.1f) {
            const float s = fric[i] * DT;
            nvx -= nvx * s;
            nvy -= nvy * s;
            nvz -= nvz * s;
        }

        float npx = pix + nvx * DT;
        float npy = piy + nvy * DT;
        float npz = piz + nvz * DT;

        // ground collision
        if (npy < 0.0f) {
            npy = 0.0f;
            nvy = -nvy * elast[i];
        }

        out[i * 3 + 0] = npx;
        out[i * 3 + 1] = npy;
        out[i * 3 + 2] = npz;
        out[NPART * 3 + i * 3 + 0] = nvx;
        out[NPART * 3 + i * 3 + 1] = nvy;
        out[NPART * 3 + i * 3 + 2] = nvz;
    }
}

extern "C" void kernel_launch(void* const* d_in, const int* in_sizes, int n_in,
                              void* d_out, int out_size, void* d_ws, size_t ws_size,
                              hipStream_t stream) {
    const float* ext   = (const float*)d_in[0];
    const float* pos   = (const float*)d_in[1];
    const float* vel   = (const float*)d_in[2];
    const float* mass  = (const float*)d_in[3];
    const float* elast = (const float*)d_in[4];
    const float* fric  = (const float*)d_in[5];
    const float* W1 = (const float*)d_in[6];
    const float* b1 = (const float*)d_in[7];
    const float* W2 = (const float*)d_in[8];
    const float* b2 = (const float*)d_in[9];
    const float* W3 = (const float*)d_in[10];
    const float* b3 = (const float*)d_in[11];
    const float* W4 = (const float*)d_in[12];
    const float* b4 = (const float*)d_in[13];
    float* out = (float*)d_out;

    particle_step_kernel<<<NPART, 256, 0, stream>>>(
        ext, pos, vel, mass, elast, fric,
        W1, b1, W2, b2, W3, b3, W4, b4, out);
}

// Round 2
// 115.807 us; speedup vs baseline: 434.6266x; 434.6266x over previous
//
#include <hip/hip_runtime.h>
#include <math.h>

#define NPART 2048
#define DT 0.016f

typedef __attribute__((ext_vector_type(8)))  short bf16x8;   // 8 bf16 = 4 VGPRs (MFMA A/B operand)
typedef __attribute__((ext_vector_type(16))) float f32x16;   // MFMA C/D accumulator

#define MFMA(A, B, C) __builtin_amdgcn_mfma_f32_32x32x16_bf16((A), (B), (C), 0, 0, 0)

__device__ inline unsigned cvt_pk(float lo, float hi) {
    unsigned r;
    asm("v_cvt_pk_bf16_f32 %0, %1, %2" : "=v"(r) : "v"(lo), "v"(hi));
    return r;
}
// v_permlane32_swap_b32 D,S:  D' = [D.lanes0-31, S.lanes0-31];  S' = [D.lanes32-63, S.lanes32-63]
__device__ inline void swap32(unsigned &x, unsigned &y) {
    asm("v_permlane32_swap_b32 %0, %1" : "+v"(x), "+v"(y));
}
__device__ inline bf16x8 mk8(unsigned a, unsigned b, unsigned c, unsigned d) {
    union { unsigned u[4]; bf16x8 s; } u;
    u.u[0] = a; u.u[1] = b; u.u[2] = c; u.u[3] = d;
    return u.s;
}
__device__ inline bf16x8 pack8(const float f[8]) {
    return mk8(cvt_pk(f[0], f[1]), cvt_pk(f[2], f[3]), cvt_pk(f[4], f[5]), cvt_pk(f[6], f[7]));
}

// D-tile (rows = 32 neurons, cols = 32 edges) -> two B k-groups (k = neuron) for the next
// layer, with relu. Uses the verified 32x32 C/D map: row = (reg&3)+8*(reg>>2)+4*(lane>>5),
// col = lane&31, and B map col = lane&31, k = 8*(lane>>5)+elem.
__device__ inline void d2b(const f32x16 &d, bf16x8 &blo, bf16x8 &bhi) {
    float r[16];
#pragma unroll
    for (int t = 0; t < 16; ++t) r[t] = fmaxf(d[t], 0.f);
    unsigned p01 = cvt_pk(r[0], r[1]),  p23 = cvt_pk(r[2], r[3]);
    unsigned p45 = cvt_pk(r[4], r[5]),  p67 = cvt_pk(r[6], r[7]);
    swap32(p01, p45);   // p01 -> dword0 (k 0,1 | 8,9),  p45 -> dword2 (k 4,5 | 12,13)
    swap32(p23, p67);   // p23 -> dword1,                p67 -> dword3
    blo = mk8(p01, p23, p45, p67);
    unsigned q01 = cvt_pk(r[8], r[9]),   q23 = cvt_pk(r[10], r[11]);
    unsigned q45 = cvt_pk(r[12], r[13]), q67 = cvt_pk(r[14], r[15]);
    swap32(q01, q45);
    swap32(q23, q67);
    bhi = mk8(q01, q23, q45, q67);
}

// One block per particle i (2048 blocks x 256 threads = 4 waves).
// Wave w handles j-tiles T = w*16 .. w*16+15 (32 j's per tile).
// Whole MLP runs on MFMA; layer-to-layer handoff is in-register (cvt_pk + permlane32_swap).
__global__ __launch_bounds__(256) void particle_step_kernel(
    const float* __restrict__ ext,  const float* __restrict__ pos,
    const float* __restrict__ vel,  const float* __restrict__ mass,
    const float* __restrict__ elast, const float* __restrict__ fric,
    const float* __restrict__ W1, const float* __restrict__ b1,
    const float* __restrict__ W2, const float* __restrict__ b2,
    const float* __restrict__ W3, const float* __restrict__ b3,
    const float* __restrict__ W4, const float* __restrict__ b4,
    float* __restrict__ out)
{
    const int l = threadIdx.x & 63;   // lane
    const int c = l & 31;             // MFMA col = edge-in-tile / also A row = neuron
    const int h = l >> 5;             // lane half (k-group half)
    const int w = threadIdx.x >> 6;   // wave id
    const int i = blockIdx.x;

    // ---------------- weight A-fragments (A[m][k] = W[k][m]; bias in gate k-slot) -------------
    bf16x8 a1[2];            // L1: K=16  (k0-7 = features, k8 = bias gate)
    bf16x8 a2[2][5];         // L2: K=80  (k0-63 = h1, k64 = bias gate)
    bf16x8 a3[5];            // L3: K=80
    bf16x8 a4[3];            // L4: K=48  (k0-31 = h3, k32 = bias gate)
#pragma unroll
    for (int mt = 0; mt < 2; ++mt) {
        const int m = c + 32 * mt;
        float f[8];
        if (h == 0) {
#pragma unroll
            for (int e = 0; e < 8; ++e) f[e] = W1[e * 64 + m];
        } else {
            f[0] = b1[m];
#pragma unroll
            for (int e = 1; e < 8; ++e) f[e] = 0.f;
        }
        a1[mt] = pack8(f);
    }
#pragma unroll
    for (int mt = 0; mt < 2; ++mt) {
        const int m = c + 32 * mt;
#pragma unroll
        for (int kg = 0; kg < 4; ++kg) {
            float f[8];
#pragma unroll
            for (int e = 0; e < 8; ++e) f[e] = W2[(kg * 16 + 8 * h + e) * 64 + m];
            a2[mt][kg] = pack8(f);
        }
        float f[8];
        f[0] = (h == 0) ? b2[m] : 0.f;
#pragma unroll
        for (int e = 1; e < 8; ++e) f[e] = 0.f;
        a2[mt][4] = pack8(f);
    }
#pragma unroll
    for (int kg = 0; kg < 4; ++kg) {
        float f[8];
#pragma unroll
        for (int e = 0; e < 8; ++e) f[e] = W3[(kg * 16 + 8 * h + e) * 32 + c];
        a3[kg] = pack8(f);
    }
    {
        float f[8];
        f[0] = (h == 0) ? b3[c] : 0.f;
#pragma unroll
        for (int e = 1; e < 8; ++e) f[e] = 0.f;
        a3[4] = pack8(f);
    }
#pragma unroll
    for (int kg = 0; kg < 2; ++kg) {
        float f[8];
#pragma unroll
        for (int e = 0; e < 8; ++e) f[e] = (c < 3) ? W4[(kg * 16 + 8 * h + e) * 3 + c] : 0.f;
        a4[kg] = pack8(f);
    }
    {
        float f[8];
        f[0] = (h == 0 && c < 3) ? b4[c] : 0.f;
#pragma unroll
        for (int e = 1; e < 8; ++e) f[e] = 0.f;
        a4[2] = pack8(f);
    }

    // gate B-fragment: B[k_gate][e] = 1.0 for every edge (k_gate = first k of the group, h=0 half)
    const bf16x8 bgate = mk8((l < 32) ? 0x00003f80u : 0u, 0u, 0u, 0u);
    const f32x16 z = {};  // zero C operand

    // ---------------- per-i state -------------------------------------------------------------
    const float pix = pos[3 * i], piy = pos[3 * i + 1], piz = pos[3 * i + 2];
    const float vix = vel[3 * i], viy = vel[3 * i + 1], viz = vel[3 * i + 2];
    const float mi = mass[i];

    float Fx = 0.f, Fy = 0.f, Fz = 0.f;

    for (int t = 0; t < 16; ++t) {
        const int T = w * 16 + t;
        const int j = T * 32 + c;

        // ---- features (fp32; both halves compute, only lanes<32 feed the MFMA) ----
        const float pjx = pos[3 * j], pjy = pos[3 * j + 1], pjz = pos[3 * j + 2];
        const float vjx = vel[3 * j], vjy = vel[3 * j + 1], vjz = vel[3 * j + 2];
        const float mj = mass[j];
        const float rx = pjx - pix, ry = pjy - piy, rz = pjz - piz;
        const float sx = vjx - vix, sy = vjy - viy, sz = vjz - viz;
        const float dist = sqrtf(rx * rx + ry * ry + rz * rz);
        const float ratio = mi / mj;
        const bool valid = (dist < 1.0f) && (j != i);

        bf16x8 bf;
        if (l < 32)
            bf = mk8(cvt_pk(rx, ry), cvt_pk(rz, sx), cvt_pk(sy, sz), cvt_pk(dist, ratio));
        else
            bf = mk8(0x00003f80u, 0u, 0u, 0u);   // k=8 bias-gate = 1.0

        // ---- L1: 2 MFMAs ----
        f32x16 acc0 = MFMA(a1[0], bf, z);
        f32x16 acc1 = MFMA(a1[1], bf, z);

        // ---- h1 -> B2 (in-register) ----
        bf16x8 bn[4];
        d2b(acc0, bn[0], bn[1]);
        d2b(acc1, bn[2], bn[3]);

        // ---- L2: 10 MFMAs ----
        acc0 = MFMA(a2[0][0], bn[0], z);
        acc0 = MFMA(a2[0][1], bn[1], acc0);
        acc0 = MFMA(a2[0][2], bn[2], acc0);
        acc0 = MFMA(a2[0][3], bn[3], acc0);
        acc0 = MFMA(a2[0][4], bgate, acc0);
        acc1 = MFMA(a2[1][0], bn[0], z);
        acc1 = MFMA(a2[1][1], bn[1], acc1);
        acc1 = MFMA(a2[1][2], bn[2], acc1);
        acc1 = MFMA(a2[1][3], bn[3], acc1);
        acc1 = MFMA(a2[1][4], bgate, acc1);

        // ---- h2 -> B3 ----
        d2b(acc0, bn[0], bn[1]);
        d2b(acc1, bn[2], bn[3]);

        // ---- L3: 5 MFMAs ----
        f32x16 acc3 = MFMA(a3[0], bn[0], z);
        acc3 = MFMA(a3[1], bn[1], acc3);
        acc3 = MFMA(a3[2], bn[2], acc3);
        acc3 = MFMA(a3[3], bn[3], acc3);
        acc3 = MFMA(a3[4], bgate, acc3);

        // ---- h3 -> B4 ----
        bf16x8 b4lo, b4hi;
        d2b(acc3, b4lo, b4hi);

        // ---- L4: 3 MFMAs ----
        f32x16 o = MFMA(a4[0], b4lo, z);
        o = MFMA(a4[1], b4hi, o);
        o = MFMA(a4[2], bgate, o);

        // ---- per-edge force components live in regs 0..2 of lane c (<32) = this edge's lane ----
        if (l < 32 && valid) {
            Fx += tanhf(o[0]) * 10.f;
            Fy += tanhf(o[1]) * 10.f;
            Fz += tanhf(o[2]) * 10.f;
        }
    }

    // ---- reduce 32 edge-lanes (lanes>=32 hold 0) then across the 4 waves ----
#pragma unroll
    for (int off = 1; off < 64; off <<= 1) {
        Fx += __shfl_xor(Fx, off);
        Fy += __shfl_xor(Fy, off);
        Fz += __shfl_xor(Fz, off);
    }
    __shared__ float red[4][3];
    if ((threadIdx.x & 63) == 0) { red[w][0] = Fx; red[w][1] = Fy; red[w][2] = Fz; }
    __syncthreads();

    if (threadIdx.x == 0) {
        float FX = red[0][0] + red[1][0] + red[2][0] + red[3][0];
        float FY = red[0][1] + red[1][1] + red[2][1] + red[3][1];
        float FZ = red[0][2] + red[1][2] + red[2][2] + red[3][2];

        FX += ext[3 * i + 0];
        FY += ext[3 * i + 1] + (-9.8f) * mi;
        FZ += ext[3 * i + 2];

        const float inv_m = 1.0f / mi;
        float nvx = vix + FX * inv_m * DT;
        float nvy = viy + FY * inv_m * DT;
        float nvz = viz + FZ * inv_m * DT;

        const float speed = sqrtf(nvx * nvx + nvy * nvy + nvz * nvz);
        if (speed > 0.1f) {
            const float s = fric[i] * DT;
            nvx -= nvx * s;
            nvy -= nvy * s;
            nvz -= nvz * s;
        }

        float npx = pix + nvx * DT;
        float npy = piy + nvy * DT;
        float npz = piz + nvz * DT;

        if (npy < 0.0f) {
            npy = 0.0f;
            nvy = -nvy * elast[i];
        }

        out[3 * i + 0] = npx;
        out[3 * i + 1] = npy;
        out[3 * i + 2] = npz;
        out[NPART * 3 + 3 * i + 0] = nvx;
        out[NPART * 3 + 3 * i + 1] = nvy;
        out[NPART * 3 + 3 * i + 2] = nvz;
    }
}

extern "C" void kernel_launch(void* const* d_in, const int* in_sizes, int n_in,
                              void* d_out, int out_size, void* d_ws, size_t ws_size,
                              hipStream_t stream) {
    const float* ext   = (const float*)d_in[0];
    const float* pos   = (const float*)d_in[1];
    const float* vel   = (const float*)d_in[2];
    const float* mass  = (const float*)d_in[3];
    const float* elast = (const float*)d_in[4];
    const float* fric  = (const float*)d_in[5];
    const float* W1 = (const float*)d_in[6];
    const float* b1 = (const float*)d_in[7];
    const float* W2 = (const float*)d_in[8];
    const float* b2 = (const float*)d_in[9];
    const float* W3 = (const float*)d_in[10];
    const float* b3 = (const float*)d_in[11];
    const float* W4 = (const float*)d_in[12];
    const float* b4 = (const float*)d_in[13];
    float* out = (float*)d_out;

    particle_step_kernel<<<NPART, 256, 0, stream>>>(
        ext, pos, vel, mass, elast, fric,
        W1, b1, W2, b2, W3, b3, W4, b4, out);
}